// Round 1
// baseline (135.886 us; speedup 1.0000x reference)
//
#include <hip/hip_runtime.h>
#include <math.h>

#define EPS 1e-12f

// ---------------------------------------------------------------------------
// Kernel A: d[b,h,w] = p_out(b,h,w) - p_gt(b,h,w),  p = ||x||_c^2 / max(||x||_c, EPS)
// One block of 256 threads per (b, h) row. Threads = (w-quad) x (channel-group).
// Coalesced float4 loads; LDS reduce over channel groups.
// ---------------------------------------------------------------------------
template <int W, int C, int H>
__global__ __launch_bounds__(256) void norm_diff_kernel(
    const float* __restrict__ xo, const float* __restrict__ xg,
    float* __restrict__ d)
{
    constexpr int QUADS  = W / 4;        // float4 groups per row
    constexpr int CCHUNK = 256 / QUADS;  // channel groups
    constexpr int CPT    = C / CCHUNK;   // channels per thread

    const int bh   = blockIdx.x;         // b*H + h
    const int tid  = threadIdx.x;
    const int quad = tid % QUADS;
    const int cgrp = tid / QUADS;
    const int b    = bh / H;
    const int h    = bh % H;

    const int plane = H * W;
    const int base  = b * C * plane + h * W + quad * 4;
    const int c0    = cgrp * CPT;

    float4 so = make_float4(0.f, 0.f, 0.f, 0.f);
    float4 sg = make_float4(0.f, 0.f, 0.f, 0.f);
#pragma unroll 4
    for (int i = 0; i < CPT; ++i) {
        const int off = base + (c0 + i) * plane;
        const float4 vo = *reinterpret_cast<const float4*>(xo + off);
        const float4 vg = *reinterpret_cast<const float4*>(xg + off);
        so.x = fmaf(vo.x, vo.x, so.x);
        so.y = fmaf(vo.y, vo.y, so.y);
        so.z = fmaf(vo.z, vo.z, so.z);
        so.w = fmaf(vo.w, vo.w, so.w);
        sg.x = fmaf(vg.x, vg.x, sg.x);
        sg.y = fmaf(vg.y, vg.y, sg.y);
        sg.z = fmaf(vg.z, vg.z, sg.z);
        sg.w = fmaf(vg.w, vg.w, sg.w);
    }

    __shared__ float lds[2][CCHUNK][W];
    *reinterpret_cast<float4*>(&lds[0][cgrp][quad * 4]) = so;
    *reinterpret_cast<float4*>(&lds[1][cgrp][quad * 4]) = sg;
    __syncthreads();

    if (tid < W) {
        float ao = 0.f, ag = 0.f;
#pragma unroll
        for (int g = 0; g < CCHUNK; ++g) {
            ao += lds[0][g][tid];
            ag += lds[1][g][tid];
        }
        const float no = sqrtf(ao);
        const float ng = sqrtf(ag);
        const float po = ao / fmaxf(no, EPS);  // norm^2 / max(norm, eps)
        const float pg = ag / fmaxf(ng, EPS);
        d[bh * W + tid] = po - pg;
    }
}

// ---------------------------------------------------------------------------
// Kernel B: for each (tensor t, batch b, kernel k): sum over valid pixels of
// boxsum_k(d)^2, scaled by 1/(B * V * V), atomically accumulated into out.
// Separable window sums entirely in LDS. Grid = 2*8*3 = 48 blocks.
// ---------------------------------------------------------------------------
__global__ __launch_bounds__(256) void boxmse_kernel(
    const float* __restrict__ d0, const float* __restrict__ d1,
    float* __restrict__ out)
{
    __shared__ float img[64 * 64];
    __shared__ float rows[64 * 64];
    __shared__ float wsum[4];

    const int bid = blockIdx.x;          // [0, 48)
    const int t   = bid / 24;            // tensor 0/1
    const int rem = bid % 24;
    const int b   = rem / 3;
    const int ki  = rem % 3;
    const int k   = 3 + 2 * ki;          // 3, 5, 7
    const int H   = (t == 0) ? 64 : 32;
    const float* src = ((t == 0) ? d0 : d1) + b * H * H;

    const int tid = threadIdx.x;
    const int N   = H * H;
    for (int i = tid; i < N; i += 256) img[i] = src[i];
    __syncthreads();

    const int V = H - k + 1;             // valid output size

    // row window sums: rows[h*V + w] = sum_{j<k} img[h*H + w + j]
    for (int i = tid; i < H * V; i += 256) {
        const int h = i / V;
        const int w = i - h * V;
        float s = 0.f;
        for (int j = 0; j < k; ++j) s += img[h * H + w + j];
        rows[h * V + w] = s;
    }
    __syncthreads();

    // column window sums + squared accumulate
    float acc = 0.f;
    for (int i = tid; i < V * V; i += 256) {
        const int y = i / V;
        const int x = i - y * V;
        float s = 0.f;
        for (int j = 0; j < k; ++j) s += rows[(y + j) * V + x];
        acc = fmaf(s, s, acc);
    }

    // block reduction (wave64 shuffle, then LDS across 4 waves)
    for (int off = 32; off > 0; off >>= 1) acc += __shfl_down(acc, off);
    if ((tid & 63) == 0) wsum[tid >> 6] = acc;
    __syncthreads();
    if (tid == 0) {
        const float total = wsum[0] + wsum[1] + wsum[2] + wsum[3];
        const float inv_count = 1.0f / (float)(8 * V * V);  // mean over [B, V, V]
        atomicAdd(out, total * inv_count);
    }
}

extern "C" void kernel_launch(void* const* d_in, const int* in_sizes, int n_in,
                              void* d_out, int out_size, void* d_ws, size_t ws_size,
                              hipStream_t stream) {
    // setup_inputs order: out_feat0, out_feat1, gt_feat0, gt_feat1
    const float* out_feat0 = (const float*)d_in[0];  // [8, 256, 64, 64]
    const float* out_feat1 = (const float*)d_in[1];  // [8, 512, 32, 32]
    const float* gt_feat0  = (const float*)d_in[2];
    const float* gt_feat1  = (const float*)d_in[3];
    float* out = (float*)d_out;

    float* d0 = (float*)d_ws;            // 8*64*64 floats
    float* d1 = d0 + 8 * 64 * 64;        // 8*32*32 floats

    hipMemsetAsync(d_out, 0, sizeof(float), stream);

    norm_diff_kernel<64, 256, 64><<<8 * 64, 256, 0, stream>>>(out_feat0, gt_feat0, d0);
    norm_diff_kernel<32, 512, 32><<<8 * 32, 256, 0, stream>>>(out_feat1, gt_feat1, d1);
    boxmse_kernel<<<48, 256, 0, stream>>>(d0, d1, out);
}

// Round 2
// 130.901 us; speedup vs baseline: 1.0381x; 1.0381x over previous
//
#include <hip/hip_runtime.h>
#include <math.h>

#define EPS 1e-12f

// ---------------------------------------------------------------------------
// Stage 1 (fused): d[b,h,w] = p_out(b,h,w) - p_gt(b,h,w)
//   p = ||x||_c^2 / max(||x||_c, EPS)
// One block of 256 threads per (tensor, b, h) row. Threads = (w-quad) x
// (channel-group). Coalesced float4 loads; LDS reduce over channel groups.
// Block 0 also zeroes the output scalar (stage 2 atomicAdds into it).
// ---------------------------------------------------------------------------
template <int W, int C, int H>
__device__ __forceinline__ void norm_diff_row(
    const float* __restrict__ xo, const float* __restrict__ xg,
    float* __restrict__ d, int bh, int tid, float* lds /* 2048 floats */)
{
    constexpr int QUADS  = W / 4;        // float4 groups per row
    constexpr int CCHUNK = 256 / QUADS;  // channel groups
    constexpr int CPT    = C / CCHUNK;   // channels per thread
    static_assert(2 * CCHUNK * W == 2048, "lds size");

    const int quad = tid % QUADS;
    const int cgrp = tid / QUADS;
    const int b    = bh / H;
    const int h    = bh % H;

    const int plane = H * W;
    const int base  = b * C * plane + h * W + quad * 4;
    const int c0    = cgrp * CPT;

    float4 so = make_float4(0.f, 0.f, 0.f, 0.f);
    float4 sg = make_float4(0.f, 0.f, 0.f, 0.f);
#pragma unroll 4
    for (int i = 0; i < CPT; ++i) {
        const int off = base + (c0 + i) * plane;
        const float4 vo = *reinterpret_cast<const float4*>(xo + off);
        const float4 vg = *reinterpret_cast<const float4*>(xg + off);
        so.x = fmaf(vo.x, vo.x, so.x);
        so.y = fmaf(vo.y, vo.y, so.y);
        so.z = fmaf(vo.z, vo.z, so.z);
        so.w = fmaf(vo.w, vo.w, so.w);
        sg.x = fmaf(vg.x, vg.x, sg.x);
        sg.y = fmaf(vg.y, vg.y, sg.y);
        sg.z = fmaf(vg.z, vg.z, sg.z);
        sg.w = fmaf(vg.w, vg.w, sg.w);
    }

    // lds layout: [2][CCHUNK][W]
    *reinterpret_cast<float4*>(lds + (0 * CCHUNK + cgrp) * W + quad * 4) = so;
    *reinterpret_cast<float4*>(lds + (1 * CCHUNK + cgrp) * W + quad * 4) = sg;
    __syncthreads();

    if (tid < W) {
        float ao = 0.f, ag = 0.f;
#pragma unroll
        for (int g = 0; g < CCHUNK; ++g) {
            ao += lds[(0 * CCHUNK + g) * W + tid];
            ag += lds[(1 * CCHUNK + g) * W + tid];
        }
        const float no = sqrtf(ao);
        const float ng = sqrtf(ag);
        const float po = ao / fmaxf(no, EPS);  // norm^2 / max(norm, eps)
        const float pg = ag / fmaxf(ng, EPS);
        d[bh * W + tid] = po - pg;
    }
}

__global__ __launch_bounds__(256) void stage1_kernel(
    const float* __restrict__ o0, const float* __restrict__ g0,
    const float* __restrict__ o1, const float* __restrict__ g1,
    float* __restrict__ d0, float* __restrict__ d1,
    float* __restrict__ out)
{
    __shared__ float lds[2048];
    const int bid = blockIdx.x;
    if (bid == 0 && threadIdx.x == 0) out[0] = 0.0f;  // stage 2 atomicAdds
    if (bid < 8 * 64) {
        norm_diff_row<64, 256, 64>(o0, g0, d0, bid, threadIdx.x, lds);
    } else {
        norm_diff_row<32, 512, 32>(o1, g1, d1, bid - 8 * 64, threadIdx.x, lds);
    }
}

// ---------------------------------------------------------------------------
// Stage 2: for each (tensor t, batch b, kernel k): sum over valid pixels of
// boxsum_k(d)^2, scaled by 1/(B * V * V), atomically accumulated into out.
// Separable window sums entirely in LDS. Grid = 2*8*3 = 48 blocks.
// ---------------------------------------------------------------------------
__global__ __launch_bounds__(256) void boxmse_kernel(
    const float* __restrict__ d0, const float* __restrict__ d1,
    float* __restrict__ out)
{
    __shared__ float img[64 * 64];
    __shared__ float rows[64 * 64];
    __shared__ float wsum[4];

    const int bid = blockIdx.x;          // [0, 48)
    const int t   = bid / 24;            // tensor 0/1
    const int rem = bid % 24;
    const int b   = rem / 3;
    const int ki  = rem % 3;
    const int k   = 3 + 2 * ki;          // 3, 5, 7
    const int H   = (t == 0) ? 64 : 32;
    const float* src = ((t == 0) ? d0 : d1) + b * H * H;

    const int tid = threadIdx.x;
    const int N   = H * H;
    for (int i = tid; i < N; i += 256) img[i] = src[i];
    __syncthreads();

    const int V = H - k + 1;             // valid output size

    // row window sums: rows[h*V + w] = sum_{j<k} img[h*H + w + j]
    for (int i = tid; i < H * V; i += 256) {
        const int h = i / V;
        const int w = i - h * V;
        float s = 0.f;
        for (int j = 0; j < k; ++j) s += img[h * H + w + j];
        rows[h * V + w] = s;
    }
    __syncthreads();

    // column window sums + squared accumulate
    float acc = 0.f;
    for (int i = tid; i < V * V; i += 256) {
        const int y = i / V;
        const int x = i - y * V;
        float s = 0.f;
        for (int j = 0; j < k; ++j) s += rows[(y + j) * V + x];
        acc = fmaf(s, s, acc);
    }

    // block reduction (wave64 shuffle, then LDS across 4 waves)
    for (int off = 32; off > 0; off >>= 1) acc += __shfl_down(acc, off);
    if ((tid & 63) == 0) wsum[tid >> 6] = acc;
    __syncthreads();
    if (tid == 0) {
        const float total = wsum[0] + wsum[1] + wsum[2] + wsum[3];
        const float inv_count = 1.0f / (float)(8 * V * V);  // mean over [B, V, V]
        atomicAdd(out, total * inv_count);
    }
}

extern "C" void kernel_launch(void* const* d_in, const int* in_sizes, int n_in,
                              void* d_out, int out_size, void* d_ws, size_t ws_size,
                              hipStream_t stream) {
    // setup_inputs order: out_feat0, out_feat1, gt_feat0, gt_feat1
    const float* out_feat0 = (const float*)d_in[0];  // [8, 256, 64, 64]
    const float* out_feat1 = (const float*)d_in[1];  // [8, 512, 32, 32]
    const float* gt_feat0  = (const float*)d_in[2];
    const float* gt_feat1  = (const float*)d_in[3];
    float* out = (float*)d_out;

    float* d0 = (float*)d_ws;            // 8*64*64 floats
    float* d1 = d0 + 8 * 64 * 64;        // 8*32*32 floats

    stage1_kernel<<<8 * 64 + 8 * 32, 256, 0, stream>>>(
        out_feat0, gt_feat0, out_feat1, gt_feat1, d0, d1, out);
    boxmse_kernel<<<48, 256, 0, stream>>>(d0, d1, out);
}

// Round 3
// 128.660 us; speedup vs baseline: 1.0562x; 1.0174x over previous
//
#include <hip/hip_runtime.h>
#include <math.h>

#define EPS 1e-12f

typedef float f4 __attribute__((ext_vector_type(4)));

// ---------------------------------------------------------------------------
// Stage 1 (fused over both tensors): per (b,h) row
//   d[w] = p_out - p_gt,  p = ||x||_c^2 / max(||x||_c, EPS)
// then k-window ROW sums r_k[w] = sum_{j<k} d[w+j] for k in {3,5,7}, stored
// to ws. This deletes stage 2's row pass. 256 threads = (w-quad)x(ch-group),
// nontemporal float4 loads (read-once stream), LDS reduce across ch-groups.
// Block 0 zeroes the output scalar (stage 2 atomicAdds into it).
// ---------------------------------------------------------------------------
template <int W, int C, int H>
__device__ __forceinline__ void row_kernel(
    const float* __restrict__ xo, const float* __restrict__ xg,
    float* __restrict__ r,     // [3][8*H][W] window row-sums per k
    int bh, int tid, float* lds /* 2048 floats */, float* drow /* W floats */)
{
    constexpr int QUADS  = W / 4;        // float4 groups per row
    constexpr int CCHUNK = 256 / QUADS;  // channel groups
    constexpr int CPT    = C / CCHUNK;   // channels per thread
    constexpr int NR     = 8 * H;        // total rows for this tensor

    const int quad = tid % QUADS;
    const int cgrp = tid / QUADS;
    const int b    = bh / H;
    const int h    = bh % H;

    const int plane = H * W;
    const int base  = b * C * plane + h * W + quad * 4;
    const int c0    = cgrp * CPT;

    f4 so = {0.f, 0.f, 0.f, 0.f};
    f4 sg = {0.f, 0.f, 0.f, 0.f};
#pragma unroll 4
    for (int i = 0; i < CPT; ++i) {
        const int off = base + (c0 + i) * plane;
        const f4 vo = __builtin_nontemporal_load(reinterpret_cast<const f4*>(xo + off));
        const f4 vg = __builtin_nontemporal_load(reinterpret_cast<const f4*>(xg + off));
        so += vo * vo;
        sg += vg * vg;
    }

    // lds layout: [2][CCHUNK][W]
    *reinterpret_cast<f4*>(lds + (0 * CCHUNK + cgrp) * W + quad * 4) = so;
    *reinterpret_cast<f4*>(lds + (1 * CCHUNK + cgrp) * W + quad * 4) = sg;
    __syncthreads();

    if (tid < W) {
        float ao = 0.f, ag = 0.f;
#pragma unroll
        for (int g = 0; g < CCHUNK; ++g) {
            ao += lds[(0 * CCHUNK + g) * W + tid];
            ag += lds[(1 * CCHUNK + g) * W + tid];
        }
        const float no = sqrtf(ao);
        const float ng = sqrtf(ag);
        const float po = ao / fmaxf(no, EPS);  // norm^2 / max(norm, eps)
        const float pg = ag / fmaxf(ng, EPS);
        drow[tid] = po - pg;
    }
    __syncthreads();

    // k-window row sums, coalesced store to ws
#pragma unroll
    for (int ki = 0; ki < 3; ++ki) {
        const int k = 3 + 2 * ki;
        const int V = W - k + 1;
        if (tid < V) {
            float s = 0.f;
#pragma unroll
            for (int j = 0; j < 7; ++j)
                if (j < k) s += drow[tid + j];
            r[(ki * NR + bh) * W + tid] = s;
        }
    }
}

__global__ __launch_bounds__(256) void stage1_kernel(
    const float* __restrict__ o0, const float* __restrict__ g0,
    const float* __restrict__ o1, const float* __restrict__ g1,
    float* __restrict__ r0, float* __restrict__ r1,
    float* __restrict__ out)
{
    __shared__ float lds[2048];
    __shared__ float drow[64];
    const int bid = blockIdx.x;
    if (bid == 0 && threadIdx.x == 0) out[0] = 0.0f;  // stage 2 atomicAdds
    if (bid < 8 * 64) {
        row_kernel<64, 256, 64>(o0, g0, r0, bid, threadIdx.x, lds, drow);
    } else {
        row_kernel<32, 512, 32>(o1, g1, r1, bid - 8 * 64, threadIdx.x, lds, drow);
    }
}

// ---------------------------------------------------------------------------
// Stage 2: per (tensor t, batch b, kernel k): column k-window sums of the
// precomputed row sums, square, mean, atomicAdd into out. 48 blocks.
// ---------------------------------------------------------------------------
__global__ __launch_bounds__(256) void boxmse_kernel(
    const float* __restrict__ r0, const float* __restrict__ r1,
    float* __restrict__ out)
{
    __shared__ float img[64 * 62];       // H x V, max 64*62
    __shared__ float wsum[4];

    const int bid = blockIdx.x;          // [0, 48)
    const int t   = bid / 24;            // tensor 0/1
    const int rem = bid % 24;
    const int b   = rem / 3;
    const int ki  = rem % 3;
    const int k   = 3 + 2 * ki;          // 3, 5, 7
    const int H   = (t == 0) ? 64 : 32;  // W == H
    const int V   = H - k + 1;
    const float* src = ((t == 0) ? r0 : r1) + (ki * (8 * H) + b * H) * H;

    const int tid = threadIdx.x;

    // load row-sum image [H][V] into LDS (packed stride V)
    for (int i = tid; i < H * V; i += 256) {
        const int y = i / V;
        const int x = i - y * V;
        img[i] = src[y * H + x];
    }
    __syncthreads();

    // column k-window sums + squared accumulate
    float acc = 0.f;
    for (int i = tid; i < V * V; i += 256) {
        const int y = i / V;
        const int x = i - y * V;
        float s = 0.f;
        for (int j = 0; j < k; ++j) s += img[(y + j) * V + x];
        acc = fmaf(s, s, acc);
    }

    // block reduction (wave64 shuffle, then LDS across 4 waves)
    for (int off = 32; off > 0; off >>= 1) acc += __shfl_down(acc, off);
    if ((tid & 63) == 0) wsum[tid >> 6] = acc;
    __syncthreads();
    if (tid == 0) {
        const float total = wsum[0] + wsum[1] + wsum[2] + wsum[3];
        const float inv_count = 1.0f / (float)(8 * V * V);  // mean over [B, V, V]
        atomicAdd(out, total * inv_count);
    }
}

extern "C" void kernel_launch(void* const* d_in, const int* in_sizes, int n_in,
                              void* d_out, int out_size, void* d_ws, size_t ws_size,
                              hipStream_t stream) {
    // setup_inputs order: out_feat0, out_feat1, gt_feat0, gt_feat1
    const float* out_feat0 = (const float*)d_in[0];  // [8, 256, 64, 64]
    const float* out_feat1 = (const float*)d_in[1];  // [8, 512, 32, 32]
    const float* gt_feat0  = (const float*)d_in[2];
    const float* gt_feat1  = (const float*)d_in[3];
    float* out = (float*)d_out;

    float* r0 = (float*)d_ws;                 // 3 * 512 * 64 floats
    float* r1 = r0 + 3 * 512 * 64;            // 3 * 256 * 32 floats

    stage1_kernel<<<8 * 64 + 8 * 32, 256, 0, stream>>>(
        out_feat0, gt_feat0, out_feat1, gt_feat1, r0, r1, out);
    boxmse_kernel<<<48, 256, 0, stream>>>(r0, r1, out);
}